// Round 6
// baseline (22.009 us; speedup 1.0000x reference)
//
#include <hip/hip_runtime.h>
#include <math.h>

#define THR_BASE 9.42477e-5f  // sin(3e-4 * pi/10): proven margin (rounds 2-5)

// Predicated (border) halo row load
#define LOADROW_P(DST, RR)                                                \
    {                                                                     \
        int rr = (RR);                                                    \
        bool rok = (rr >= 0) && (rr < 512);                               \
        const float* rp = img + (size_t)(rok ? rr : row) * 512;           \
        const float4* rp4 = (const float4*)(rp + col0);                   \
        float4 v0 = rp4[0], v1 = rp4[1];                                  \
        float lf = rp[(cw > 0) ? (col0 - 1) : col0];                      \
        float rt = rp[(cw < 63) ? (col0 + 8) : col0];                     \
        float m = rok ? 1.0f : 0.0f;                                      \
        DST[0] = (cw > 0 && rok) ? lf : 0.0f;                             \
        DST[1] = v0.x * m; DST[2] = v0.y * m;                             \
        DST[3] = v0.z * m; DST[4] = v0.w * m;                             \
        DST[5] = v1.x * m; DST[6] = v1.y * m;                             \
        DST[7] = v1.z * m; DST[8] = v1.w * m;                             \
        DST[9] = (cw < 63 && rok) ? rt : 0.0f;                            \
    }

// Unpredicated (interior-wave) halo row load
#define LOADROW_F(DST, RR)                                                \
    {                                                                     \
        const float* rp = img + (size_t)(RR) * 512;                       \
        const float4* rp4 = (const float4*)(rp + col0);                   \
        float4 v0 = rp4[0], v1 = rp4[1];                                  \
        DST[0] = rp[col0 - 1];                                            \
        DST[1] = v0.x; DST[2] = v0.y; DST[3] = v0.z; DST[4] = v0.w;       \
        DST[5] = v1.x; DST[6] = v1.y; DST[7] = v1.z; DST[8] = v1.w;       \
        DST[9] = rp[col0 + 8];                                            \
    }

// x: (16,1,512,512) f32 ; out: (16,10,64,64) f32
// thread t -> (n, ch, cw, r): r = t & 7 (pixel row within 8x8 cell)
__global__ void __launch_bounds__(256) hog_kernel(const float* __restrict__ x,
                                                  float* __restrict__ out) {
    int t    = blockIdx.x * 256 + threadIdx.x;
    int r    = t & 7;
    int cell = t >> 3;           // 0 .. 65535
    int cw   = cell & 63;
    int ch   = (cell >> 6) & 63;
    int n    = cell >> 12;

    const float* img = x + (size_t)n * (512 * 512);
    int row  = ch * 8 + r;
    int col0 = cw * 8;

    float xr0[10], xr1[10], xr2[10];
    bool border = (cw == 0) | (cw == 63) | (ch == 0) | (ch == 63);
    if (__any((int)border)) {
        LOADROW_P(xr0, row - 1)
        LOADROW_P(xr1, row)
        LOADROW_P(xr2, row + 1)
    } else {
        LOADROW_F(xr0, row - 1)
        LOADROW_F(xr1, row)
        LOADROW_F(xr2, row + 1)
    }

    // d[c]: column sums (gx = d[c]-d[c+2]); u[c]: row diffs (gy from u).
    // After this, xr0/1/2 are dead -> small hot-loop live set.
    float d[10], u[10];
#pragma unroll
    for (int c = 0; c < 10; ++c) {
        d[c] = fmaf(2.0f, xr1[c], xr0[c] + xr2[c]);
        u[c] = xr0[c] - xr2[c];
    }

    float cmagF[10];
#pragma unroll
    for (int b = 0; b < 10; ++b) cmagF[b] = 0.0f;
    unsigned long long pk = 0ull;   // 10 x 4-bit per-bin pixel counts (<=8)

#pragma unroll
    for (int c = 0; c < 8; ++c) {
        float gx = d[c] - d[c + 2];
        float gy = fmaf(2.0f, u[c + 1], u[c] + u[c + 2]);
        float mag = __builtin_amdgcn_sqrtf(fmaf(gx, gx, gy * gy));
        float a = fabsf(gx), b = fabsf(gy);

        // Sector tests: m_k = a*cos(k*pi/10) - b*sin(k*pi/10), k=1..4
        float m1 = fmaf(a, 0.95105651629515353f, -(b * 0.30901699437494740f));
        float m2 = fmaf(a, 0.80901699437494745f, -(b * 0.58778525229247314f));
        float m3 = fmaf(a, 0.58778525229247314f, -(b * 0.80901699437494745f));
        float m4 = fmaf(a, 0.30901699437494740f, -(b * 0.95105651629515353f));
        int neg = (int)(__float_as_uint(m1) >> 31) + (int)(__float_as_uint(m2) >> 31)
                + (int)(__float_as_uint(m3) >> 31) + (int)(__float_as_uint(m4) >> 31);
        bool qq = (((__float_as_uint(gx) ^ __float_as_uint(gy)) >> 31) != 0u);
        int fl = qq ? (5 + neg) : (4 - neg);

        float dmin = fminf(fminf(fminf(fabsf(m1), fabsf(m2)),
                                 fminf(fabsf(m3), fabsf(m4))),
                           fminf(a, b));
        float mval = mag;

        if (dmin < THR_BASE * fmaxf(mag, 1.0f)) {
            // Rare boundary path: reload 3x3 window (L2-hot), exact f64 conv,
            // f64 sector classification (no atan2). Axis cases: contribution
            // mag + (1-mag) = 1.0 into one bin -> encode as mval=1 at fl.
            int pc = col0 + c;
            int rm = row - 1, rq = row + 1;
            int cm = pc - 1, cp = pc + 1;
            bool rmok = rm >= 0, rqok = rq < 512;
            bool cmok = cm >= 0, cpok = cp < 512;
            float w00 = (rmok && cmok) ? img[(size_t)rm * 512 + cm] : 0.0f;
            float w01 = rmok ? img[(size_t)rm * 512 + pc] : 0.0f;
            float w02 = (rmok && cpok) ? img[(size_t)rm * 512 + cp] : 0.0f;
            float w10 = cmok ? img[(size_t)row * 512 + cm] : 0.0f;
            float w12 = cpok ? img[(size_t)row * 512 + cp] : 0.0f;
            float w20 = (rqok && cmok) ? img[(size_t)rq * 512 + cm] : 0.0f;
            float w21 = rqok ? img[(size_t)rq * 512 + pc] : 0.0f;
            float w22 = (rqok && cpok) ? img[(size_t)rq * 512 + cp] : 0.0f;

            double gxd = (((((double)w00 - (double)w02) + 2.0 * (double)w10)
                           - 2.0 * (double)w12) + (double)w20) - (double)w22;
            double gyd = (((((double)w00 + 2.0 * (double)w01) + (double)w02)
                           - (double)w20) - 2.0 * (double)w21) - (double)w22;

            if (gxd == 0.0) { fl = 0; mval = 1.0f; }          // p = 0 / +-10
            else if (gyd == 0.0) { fl = 5; mval = 1.0f; }     // p = +-5
            else {
                double ad = fabs(gxd), bd = fabs(gyd);
                double M1 = fma(ad, 0.95105651629515353118, -(bd * 0.30901699437494742410));
                double M2 = fma(ad, 0.80901699437494742410, -(bd * 0.58778525229247312917));
                double M3 = fma(ad, 0.58778525229247312917, -(bd * 0.80901699437494742410));
                double M4 = fma(ad, 0.30901699437494742410, -(bd * 0.95105651629515353118));
                int negd = (int)(M1 < 0.0) + (int)(M2 < 0.0)
                         + (int)(M3 < 0.0) + (int)(M4 < 0.0);
                bool qd = (gxd < 0.0) != (gyd < 0.0);
                fl = qd ? (5 + negd) : (4 - negd);
            }
        }

        // Unified accumulate: bin fl gets mval; bin fl+1 (mod 10) gets
        // 1 - mval via the packed count in the combine below.
#pragma unroll
        for (int bb = 0; bb < 10; ++bb)
            cmagF[bb] += (bb == fl) ? mval : 0.0f;
        pk += 1ull << (fl * 4);
    }

    // bins[b] = cmag[b] - cmag[b-1] + cnt[b-1]; 8-lane shuffle butterfly
    // (round-4-proven mechanism; DPP reverted due to replay divergence).
    float* op = out + (((size_t)n * 10) * 64 + ch) * 64 + cw;
#pragma unroll
    for (int b = 0; b < 10; ++b) {
        int bm1 = (b + 9) % 10;
        float cnt = (float)(unsigned)((pk >> (bm1 * 4)) & 15ull);
        float v = (cmagF[b] - cmagF[bm1]) + cnt;
        v += __shfl_xor(v, 1);
        v += __shfl_xor(v, 2);
        v += __shfl_xor(v, 4);
        if (r == 0) op[(size_t)b * 4096] = v * (1.0f / 64.0f);
    }
}

extern "C" void kernel_launch(void* const* d_in, const int* in_sizes, int n_in,
                              void* d_out, int out_size, void* d_ws, size_t ws_size,
                              hipStream_t stream) {
    const float* x = (const float*)d_in[0];
    float* out = (float*)d_out;
    const int total = 16 * 64 * 64 * 8;  // 524288 threads
    hog_kernel<<<total / 256, 256, 0, stream>>>(x, out);
}

// Round 7
// 20.054 us; speedup vs baseline: 1.0975x; 1.0975x over previous
//
#include <hip/hip_runtime.h>
#include <math.h>

#define THR_BASE 9.42477e-5f  // sin(3e-4 * pi/10): proven margin (rounds 2-6)

// Predicated (border) halo row load
#define LOADROW_P(DST, RR)                                                \
    {                                                                     \
        int rr = (RR);                                                    \
        bool rok = (rr >= 0) && (rr < 512);                               \
        const float* rp = img + (size_t)(rok ? rr : row) * 512;           \
        const float4* rp4 = (const float4*)(rp + col0);                   \
        float4 v0 = rp4[0], v1 = rp4[1];                                  \
        float lf = rp[(cw > 0) ? (col0 - 1) : col0];                      \
        float rt = rp[(cw < 63) ? (col0 + 8) : col0];                     \
        float m = rok ? 1.0f : 0.0f;                                      \
        DST[0] = (cw > 0 && rok) ? lf : 0.0f;                             \
        DST[1] = v0.x * m; DST[2] = v0.y * m;                             \
        DST[3] = v0.z * m; DST[4] = v0.w * m;                             \
        DST[5] = v1.x * m; DST[6] = v1.y * m;                             \
        DST[7] = v1.z * m; DST[8] = v1.w * m;                             \
        DST[9] = (cw < 63 && rok) ? rt : 0.0f;                            \
    }

// Unpredicated (interior-wave) halo row load
#define LOADROW_F(DST, RR)                                                \
    {                                                                     \
        const float* rp = img + (size_t)(RR) * 512;                       \
        const float4* rp4 = (const float4*)(rp + col0);                   \
        float4 v0 = rp4[0], v1 = rp4[1];                                  \
        DST[0] = rp[col0 - 1];                                            \
        DST[1] = v0.x; DST[2] = v0.y; DST[3] = v0.z; DST[4] = v0.w;       \
        DST[5] = v1.x; DST[6] = v1.y; DST[7] = v1.z; DST[8] = v1.w;       \
        DST[9] = rp[col0 + 8];                                            \
    }

// x: (16,1,512,512) f32 ; out: (16,10,64,64) f32
// thread t -> (n, ch, cw, r): r = t & 7 (pixel row within 8x8 cell)
// Branch-free hot loop + single out-of-loop fixup for boundary pixels.
__global__ void __launch_bounds__(256) hog_kernel(const float* __restrict__ x,
                                                  float* __restrict__ out) {
    int t    = blockIdx.x * 256 + threadIdx.x;
    int r    = t & 7;
    int cell = t >> 3;           // 0 .. 65535
    int cw   = cell & 63;
    int ch   = (cell >> 6) & 63;
    int n    = cell >> 12;

    const float* img = x + (size_t)n * (512 * 512);
    int row  = ch * 8 + r;
    int col0 = cw * 8;

    float xr0[10], xr1[10], xr2[10];
    bool border = (cw == 0) | (cw == 63) | (ch == 0) | (ch == 63);
    if (__any((int)border)) {
        LOADROW_P(xr0, row - 1)
        LOADROW_P(xr1, row)
        LOADROW_P(xr2, row + 1)
    } else {
        LOADROW_F(xr0, row - 1)
        LOADROW_F(xr1, row)
        LOADROW_F(xr2, row + 1)
    }

    // d[c]: column sums (gx = d[c]-d[c+2]); u[c]: row diffs (gy from u).
    float d[10], u[10];
#pragma unroll
    for (int c = 0; c < 10; ++c) {
        d[c] = fmaf(2.0f, xr1[c], xr0[c] + xr2[c]);
        u[c] = xr0[c] - xr2[c];
    }

    float cmagF[10];
#pragma unroll
    for (int b = 0; b < 10; ++b) cmagF[b] = 0.0f;
    unsigned long long pk = 0ull;   // 10 x 4-bit per-bin pixel counts (<=8)
    unsigned bmask = 0u;            // boundary-pixel flags (rare)

    // ---- Branch-free hot loop: always accumulate fast result ----
#pragma unroll
    for (int c = 0; c < 8; ++c) {
        float gx = d[c] - d[c + 2];
        float gy = fmaf(2.0f, u[c + 1], u[c] + u[c + 2]);
        float mag = __builtin_amdgcn_sqrtf(fmaf(gx, gx, gy * gy));
        float a = fabsf(gx), b = fabsf(gy);

        // Sector tests: m_k = a*cos(k*pi/10) - b*sin(k*pi/10), k=1..4
        float m1 = fmaf(a, 0.95105651629515353f, -(b * 0.30901699437494740f));
        float m2 = fmaf(a, 0.80901699437494745f, -(b * 0.58778525229247314f));
        float m3 = fmaf(a, 0.58778525229247314f, -(b * 0.80901699437494745f));
        float m4 = fmaf(a, 0.30901699437494740f, -(b * 0.95105651629515353f));
        int neg = (int)(__float_as_uint(m1) >> 31) + (int)(__float_as_uint(m2) >> 31)
                + (int)(__float_as_uint(m3) >> 31) + (int)(__float_as_uint(m4) >> 31);
        bool qq = (((__float_as_uint(gx) ^ __float_as_uint(gy)) >> 31) != 0u);
        int fl = qq ? (5 + neg) : (4 - neg);

        float dmin = fminf(fminf(fminf(fabsf(m1), fabsf(m2)),
                                 fminf(fabsf(m3), fabsf(m4))),
                           fminf(a, b));
        bmask = (dmin < THR_BASE * fmaxf(mag, 1.0f)) ? (bmask | (1u << c)) : bmask;

#pragma unroll
        for (int bb = 0; bb < 10; ++bb)
            cmagF[bb] += (bb == fl) ? mag : 0.0f;
        pk += 1ull << (fl * 4);
    }

    // ---- Rare fixup: undo fast contribution, apply exact f64 sector ----
    while (__any((int)(bmask != 0u))) {
        if (bmask) {
            int c = (int)__builtin_ctz(bmask);
            bmask &= bmask - 1u;
            int pc = col0 + c;
            int rm = row - 1, rq = row + 1;
            int cm = pc - 1, cp = pc + 1;
            bool rmok = rm >= 0, rqok = rq < 512;
            bool cmok = cm >= 0, cpok = cp < 512;
            float w00 = (rmok && cmok) ? img[(size_t)rm * 512 + cm] : 0.0f;
            float w01 = rmok ? img[(size_t)rm * 512 + pc] : 0.0f;
            float w02 = (rmok && cpok) ? img[(size_t)rm * 512 + cp] : 0.0f;
            float w10 = cmok ? img[(size_t)row * 512 + cm] : 0.0f;
            float w12 = cpok ? img[(size_t)row * 512 + cp] : 0.0f;
            float w20 = (rqok && cmok) ? img[(size_t)rq * 512 + cm] : 0.0f;
            float w21 = rqok ? img[(size_t)rq * 512 + pc] : 0.0f;
            float w22 = (rqok && cpok) ? img[(size_t)rq * 512 + cp] : 0.0f;

            // Bit-exact replication of the fast path (same ops, same values)
            float gxf = fmaf(2.0f, w10, w00 + w20) - fmaf(2.0f, w12, w02 + w22);
            float gyf = fmaf(2.0f, w01 - w21, (w00 - w20) + (w02 - w22));
            float magf = __builtin_amdgcn_sqrtf(fmaf(gxf, gxf, gyf * gyf));
            int negf = (int)(__float_as_uint(fmaf(fabsf(gxf), 0.95105651629515353f, -(fabsf(gyf) * 0.30901699437494740f))) >> 31)
                     + (int)(__float_as_uint(fmaf(fabsf(gxf), 0.80901699437494745f, -(fabsf(gyf) * 0.58778525229247314f))) >> 31)
                     + (int)(__float_as_uint(fmaf(fabsf(gxf), 0.58778525229247314f, -(fabsf(gyf) * 0.80901699437494745f))) >> 31)
                     + (int)(__float_as_uint(fmaf(fabsf(gxf), 0.30901699437494740f, -(fabsf(gyf) * 0.95105651629515353f))) >> 31);
            bool qqf = (((__float_as_uint(gxf) ^ __float_as_uint(gyf)) >> 31) != 0u);
            int flf = qqf ? (5 + negf) : (4 - negf);

            // Undo fast contribution
#pragma unroll
            for (int bb = 0; bb < 10; ++bb)
                cmagF[bb] -= (bb == flf) ? magf : 0.0f;
            pk -= 1ull << (flf * 4);

            // Exact f64 sector classification (no atan2).
            double gxd = (((((double)w00 - (double)w02) + 2.0 * (double)w10)
                           - 2.0 * (double)w12) + (double)w20) - (double)w22;
            double gyd = (((((double)w00 + 2.0 * (double)w01) + (double)w02)
                           - (double)w20) - 2.0 * (double)w21) - (double)w22;
            int fls;
            float mvals;
            if (gxd == 0.0) { fls = 0; mvals = 1.0f; }        // p = 0 / +-10
            else if (gyd == 0.0) { fls = 5; mvals = 1.0f; }   // p = +-5
            else {
                double ad = fabs(gxd), bd = fabs(gyd);
                double M1 = fma(ad, 0.95105651629515353118, -(bd * 0.30901699437494742410));
                double M2 = fma(ad, 0.80901699437494742410, -(bd * 0.58778525229247312917));
                double M3 = fma(ad, 0.58778525229247312917, -(bd * 0.80901699437494742410));
                double M4 = fma(ad, 0.30901699437494742410, -(bd * 0.95105651629515353118));
                int negd = (int)(M1 < 0.0) + (int)(M2 < 0.0)
                         + (int)(M3 < 0.0) + (int)(M4 < 0.0);
                bool qd = (gxd < 0.0) != (gyd < 0.0);
                fls = qd ? (5 + negd) : (4 - negd);
                mvals = magf;
            }
#pragma unroll
            for (int bb = 0; bb < 10; ++bb)
                cmagF[bb] += (bb == fls) ? mvals : 0.0f;
            pk += 1ull << (fls * 4);
        }
    }

    // bins[b] = cmag[b] - cmag[b-1] + cnt[b-1]; 8-lane shuffle butterfly
    float* op = out + (((size_t)n * 10) * 64 + ch) * 64 + cw;
#pragma unroll
    for (int b = 0; b < 10; ++b) {
        int bm1 = (b + 9) % 10;
        float cnt = (float)(unsigned)((pk >> (bm1 * 4)) & 15ull);
        float v = (cmagF[b] - cmagF[bm1]) + cnt;
        v += __shfl_xor(v, 1);
        v += __shfl_xor(v, 2);
        v += __shfl_xor(v, 4);
        if (r == 0) op[(size_t)b * 4096] = v * (1.0f / 64.0f);
    }
}

extern "C" void kernel_launch(void* const* d_in, const int* in_sizes, int n_in,
                              void* d_out, int out_size, void* d_ws, size_t ws_size,
                              hipStream_t stream) {
    const float* x = (const float*)d_in[0];
    float* out = (float*)d_out;
    const int total = 16 * 64 * 64 * 8;  // 524288 threads
    hog_kernel<<<total / 256, 256, 0, stream>>>(x, out);
}